// Round 1
// baseline (461.201 us; speedup 1.0000x reference)
//
#include <hip/hip_runtime.h>

// Neural ODE: dy/dt = tanh(W2 @ softplus(W1 @ y + b1) + b2), y in R^4, HID=32.
// B=131072 independent states, save at t_k = k*t1/99 (k=0..99), output = sum(ys).
//
// Strategy: fixed-step RK4, 33 steps (3 save intervals per step). Cubic Hermite
// dense output summed over the 3 save points per step collapses exactly to
//   sum_c [ y_c + 2*y1_c + (2h/9)*(f0_c - f1_c) ]
// so no per-point interpolation is needed. 133 MLP evals per state total.
// Global integration error ~3e-6 per element vs per-element budget ~6.5e-4.

#define NSTEPS 33
#define TPB 256

__device__ __forceinline__ float fast_tanh(float x) {
  // tanh(x) = 1 - 2/(exp(2x)+1); exact saturation at +/-inf of exp.
  float e = __expf(2.0f * x);
  return 1.0f - 2.0f * __builtin_amdgcn_rcpf(e + 1.0f);
}

__global__ __launch_bounds__(TPB) void node_kernel(
    const float* __restrict__ gy0, const float* __restrict__ gW1,
    const float* __restrict__ gb1, const float* __restrict__ gW2,
    const float* __restrict__ gb2, const float* __restrict__ gt1,
    double* __restrict__ gacc, int nbatch) {
  __shared__ float4 sW1[32];   // W1 rows (32x4)
  __shared__ float4 sW2t[32];  // W2 columns: sW2t[j] = {W2[0][j],W2[1][j],W2[2][j],W2[3][j]}
  __shared__ float sb1[32];
  __shared__ float sb2c[4];
  __shared__ float shstep;
  __shared__ double swave[TPB / 64];

  const int t = threadIdx.x;
  if (t < 32) {
    sW1[t] = reinterpret_cast<const float4*>(gW1)[t];
    sb1[t] = gb1[t];
    sW2t[t] = make_float4(gW2[t], gW2[32 + t], gW2[64 + t], gW2[96 + t]);
  } else if (t < 36) {
    sb2c[t - 32] = gb2[t - 32];
  } else if (t == 36) {
    shstep = gt1[0] / (float)NSTEPS;
  }
  __syncthreads();

  const int gid = blockIdx.x * TPB + t;
  double acc = 0.0;

  if (gid < nbatch) {
    float4 y = reinterpret_cast<const float4*>(gy0)[gid];
    const float h = shstep;
    const float b20 = sb2c[0], b21 = sb2c[1], b22 = sb2c[2], b23 = sb2c[3];

    // MLP vector field eval: f = tanh(W2 @ softplus(W1 @ y + b1) + b2)
    auto feval = [&](const float4& yy) -> float4 {
      float o0 = b20, o1 = b21, o2 = b22, o3 = b23;
#pragma unroll 8
      for (int j = 0; j < 32; ++j) {
        float4 w1 = sW1[j];
        float a = sb1[j];
        a = fmaf(w1.x, yy.x, a);
        a = fmaf(w1.y, yy.y, a);
        a = fmaf(w1.z, yy.z, a);
        a = fmaf(w1.w, yy.w, a);
        // softplus(a) = max(a,0) + log1p(exp(-|a|))
        float e = __expf(-fabsf(a));
        float sp = fmaxf(a, 0.0f) + __logf(1.0f + e);
        float4 w2 = sW2t[j];
        o0 = fmaf(w2.x, sp, o0);
        o1 = fmaf(w2.y, sp, o1);
        o2 = fmaf(w2.z, sp, o2);
        o3 = fmaf(w2.w, sp, o3);
      }
      return make_float4(fast_tanh(o0), fast_tanh(o1), fast_tanh(o2),
                         fast_tanh(o3));
    };

    // t=0 save point
    acc = (double)((y.x + y.y) + (y.z + y.w));

    float4 fc = feval(y);  // k1 of first step
    const float hh = 0.5f * h;
    const float h6 = h * (1.0f / 6.0f);
    const float c29 = (2.0f / 9.0f) * h;

#pragma unroll 1
    for (int s = 0; s < NSTEPS; ++s) {
      float4 yt;
      yt.x = fmaf(hh, fc.x, y.x);
      yt.y = fmaf(hh, fc.y, y.y);
      yt.z = fmaf(hh, fc.z, y.z);
      yt.w = fmaf(hh, fc.w, y.w);
      float4 k2 = feval(yt);
      yt.x = fmaf(hh, k2.x, y.x);
      yt.y = fmaf(hh, k2.y, y.y);
      yt.z = fmaf(hh, k2.z, y.z);
      yt.w = fmaf(hh, k2.w, y.w);
      float4 k3 = feval(yt);
      yt.x = fmaf(h, k3.x, y.x);
      yt.y = fmaf(h, k3.y, y.y);
      yt.z = fmaf(h, k3.z, y.z);
      yt.w = fmaf(h, k3.w, y.w);
      float4 k4 = feval(yt);
      float4 y1;
      y1.x = fmaf(h6, fc.x + 2.0f * (k2.x + k3.x) + k4.x, y.x);
      y1.y = fmaf(h6, fc.y + 2.0f * (k2.y + k3.y) + k4.y, y.y);
      y1.z = fmaf(h6, fc.z + 2.0f * (k2.z + k3.z) + k4.z, y.z);
      y1.w = fmaf(h6, fc.w + 2.0f * (k2.w + k3.w) + k4.w, y.w);
      float4 fn = feval(y1);  // endpoint deriv; also next step's k1

      // sum of the 3 save points in this step (Hermite dense output collapsed)
      float st = (y.x + 2.0f * y1.x + c29 * (fc.x - fn.x)) +
                 (y.y + 2.0f * y1.y + c29 * (fc.y - fn.y)) +
                 (y.z + 2.0f * y1.z + c29 * (fc.z - fn.z)) +
                 (y.w + 2.0f * y1.w + c29 * (fc.w - fn.w));
      acc += (double)st;
      y = y1;
      fc = fn;
    }
  }

  // wave (64-lane) shuffle reduction in double
#pragma unroll
  for (int off = 32; off > 0; off >>= 1) acc += __shfl_down(acc, off, 64);
  if ((t & 63) == 0) swave[t >> 6] = acc;
  __syncthreads();
  if (t == 0) {
    double b = 0.0;
#pragma unroll
    for (int w = 0; w < TPB / 64; ++w) b += swave[w];
    atomicAdd(gacc, b);
  }
}

__global__ void finalize_kernel(const double* __restrict__ acc,
                                float* __restrict__ out) {
  out[0] = (float)acc[0];
}

extern "C" void kernel_launch(void* const* d_in, const int* in_sizes, int n_in,
                              void* d_out, int out_size, void* d_ws,
                              size_t ws_size, hipStream_t stream) {
  const float* y0 = (const float*)d_in[0];
  const float* W1 = (const float*)d_in[1];
  const float* b1 = (const float*)d_in[2];
  const float* W2 = (const float*)d_in[3];
  const float* b2 = (const float*)d_in[4];
  const float* t1 = (const float*)d_in[5];

  double* acc = (double*)d_ws;
  hipMemsetAsync(d_ws, 0, sizeof(double), stream);

  const int nbatch = in_sizes[0] / 4;  // 131072
  const int blocks = (nbatch + TPB - 1) / TPB;
  node_kernel<<<blocks, TPB, 0, stream>>>(y0, W1, b1, W2, b2, t1, acc, nbatch);
  finalize_kernel<<<1, 1, 0, stream>>>(acc, (float*)d_out);
}

// Round 2
// 202.896 us; speedup vs baseline: 2.2731x; 2.2731x over previous
//
#include <hip/hip_runtime.h>

// Neural ODE: dy/dt = tanh(W2 @ softplus(W1 @ y + b1) + b2), y in R^4, HID=32.
// B=131072 independent states, save at t_k = k*t1/99 (k=0..99), output = sum(ys).
//
// Strategy: fixed-step RK4, NSTEPS=11 (9 save intervals per step; 99 = 9*11).
// Summed cubic Hermite dense output over theta=i/9, i=1..9 collapses exactly to
//   sum_c [ 4*y_c + 5*y1_c + (20/27)*h*(f0_c - f1_c) ]
// (A=(n-1)/2, B=(n+1)/2, C=(n^2-1)/(12n), D=-C for n saves/step).
// 45 MLP evals per state (FSAL reuse) vs 133 at NSTEPS=33 -> ~3x less VALU work.
// RK4 global error ~7e-5/elem at h=1/11; Hermite interp error ~2e-7. Scalar-sum
// threshold 3.4e4 over 52.4M summed elements -> safe by >10x even if correlated.

#define NSTEPS 11
#define TPB 256

__device__ __forceinline__ float fast_tanh(float x) {
  // tanh(x) = 1 - 2/(exp(2x)+1); exact saturation at +/-inf of exp.
  float e = __expf(2.0f * x);
  return 1.0f - 2.0f * __builtin_amdgcn_rcpf(e + 1.0f);
}

__global__ __launch_bounds__(TPB) void node_kernel(
    const float* __restrict__ gy0, const float* __restrict__ gW1,
    const float* __restrict__ gb1, const float* __restrict__ gW2,
    const float* __restrict__ gb2, const float* __restrict__ gt1,
    double* __restrict__ gacc, int nbatch) {
  __shared__ float4 sW1[32];   // W1 rows (32x4)
  __shared__ float4 sW2t[32];  // W2 columns: sW2t[j] = {W2[0][j],W2[1][j],W2[2][j],W2[3][j]}
  __shared__ float sb1[32];
  __shared__ float sb2c[4];
  __shared__ float shstep;
  __shared__ double swave[TPB / 64];

  const int t = threadIdx.x;
  if (t < 32) {
    sW1[t] = reinterpret_cast<const float4*>(gW1)[t];
    sb1[t] = gb1[t];
    sW2t[t] = make_float4(gW2[t], gW2[32 + t], gW2[64 + t], gW2[96 + t]);
  } else if (t < 36) {
    sb2c[t - 32] = gb2[t - 32];
  } else if (t == 36) {
    shstep = gt1[0] / (float)NSTEPS;
  }
  __syncthreads();

  const int gid = blockIdx.x * TPB + t;
  double acc = 0.0;

  if (gid < nbatch) {
    float4 y = reinterpret_cast<const float4*>(gy0)[gid];
    const float h = shstep;
    const float b20 = sb2c[0], b21 = sb2c[1], b22 = sb2c[2], b23 = sb2c[3];

    // MLP vector field eval: f = tanh(W2 @ softplus(W1 @ y + b1) + b2)
    auto feval = [&](const float4& yy) -> float4 {
      float o0 = b20, o1 = b21, o2 = b22, o3 = b23;
#pragma unroll 8
      for (int j = 0; j < 32; ++j) {
        float4 w1 = sW1[j];
        float a = sb1[j];
        a = fmaf(w1.x, yy.x, a);
        a = fmaf(w1.y, yy.y, a);
        a = fmaf(w1.z, yy.z, a);
        a = fmaf(w1.w, yy.w, a);
        // softplus(a) = max(a,0) + log1p(exp(-|a|))
        float e = __expf(-fabsf(a));
        float sp = fmaxf(a, 0.0f) + __logf(1.0f + e);
        float4 w2 = sW2t[j];
        o0 = fmaf(w2.x, sp, o0);
        o1 = fmaf(w2.y, sp, o1);
        o2 = fmaf(w2.z, sp, o2);
        o3 = fmaf(w2.w, sp, o3);
      }
      return make_float4(fast_tanh(o0), fast_tanh(o1), fast_tanh(o2),
                         fast_tanh(o3));
    };

    // t=0 save point
    acc = (double)((y.x + y.y) + (y.z + y.w));

    float4 fc = feval(y);  // k1 of first step
    const float hh = 0.5f * h;
    const float h6 = h * (1.0f / 6.0f);
    const float cC = (20.0f / 27.0f) * h;  // dense-output deriv coeff (n=9)

#pragma unroll 1
    for (int s = 0; s < NSTEPS; ++s) {
      float4 yt;
      yt.x = fmaf(hh, fc.x, y.x);
      yt.y = fmaf(hh, fc.y, y.y);
      yt.z = fmaf(hh, fc.z, y.z);
      yt.w = fmaf(hh, fc.w, y.w);
      float4 k2 = feval(yt);
      yt.x = fmaf(hh, k2.x, y.x);
      yt.y = fmaf(hh, k2.y, y.y);
      yt.z = fmaf(hh, k2.z, y.z);
      yt.w = fmaf(hh, k2.w, y.w);
      float4 k3 = feval(yt);
      yt.x = fmaf(h, k3.x, y.x);
      yt.y = fmaf(h, k3.y, y.y);
      yt.z = fmaf(h, k3.z, y.z);
      yt.w = fmaf(h, k3.w, y.w);
      float4 k4 = feval(yt);
      float4 y1;
      y1.x = fmaf(h6, fc.x + 2.0f * (k2.x + k3.x) + k4.x, y.x);
      y1.y = fmaf(h6, fc.y + 2.0f * (k2.y + k3.y) + k4.y, y.y);
      y1.z = fmaf(h6, fc.z + 2.0f * (k2.z + k3.z) + k4.z, y.z);
      y1.w = fmaf(h6, fc.w + 2.0f * (k2.w + k3.w) + k4.w, y.w);
      float4 fn = feval(y1);  // endpoint deriv; also next step's k1 (FSAL)

      // sum of the 9 save points in this step (Hermite dense output collapsed)
      float st = (4.0f * y.x + 5.0f * y1.x + cC * (fc.x - fn.x)) +
                 (4.0f * y.y + 5.0f * y1.y + cC * (fc.y - fn.y)) +
                 (4.0f * y.z + 5.0f * y1.z + cC * (fc.z - fn.z)) +
                 (4.0f * y.w + 5.0f * y1.w + cC * (fc.w - fn.w));
      acc += (double)st;
      y = y1;
      fc = fn;
    }
  }

  // wave (64-lane) shuffle reduction in double
#pragma unroll
  for (int off = 32; off > 0; off >>= 1) acc += __shfl_down(acc, off, 64);
  if ((t & 63) == 0) swave[t >> 6] = acc;
  __syncthreads();
  if (t == 0) {
    double b = 0.0;
#pragma unroll
    for (int w = 0; w < TPB / 64; ++w) b += swave[w];
    atomicAdd(gacc, b);
  }
}

__global__ void finalize_kernel(const double* __restrict__ acc,
                                float* __restrict__ out) {
  out[0] = (float)acc[0];
}

extern "C" void kernel_launch(void* const* d_in, const int* in_sizes, int n_in,
                              void* d_out, int out_size, void* d_ws,
                              size_t ws_size, hipStream_t stream) {
  const float* y0 = (const float*)d_in[0];
  const float* W1 = (const float*)d_in[1];
  const float* b1 = (const float*)d_in[2];
  const float* W2 = (const float*)d_in[3];
  const float* b2 = (const float*)d_in[4];
  const float* t1 = (const float*)d_in[5];

  double* acc = (double*)d_ws;
  hipMemsetAsync(d_ws, 0, sizeof(double), stream);

  const int nbatch = in_sizes[0] / 4;  // 131072
  const int blocks = (nbatch + TPB - 1) / TPB;
  node_kernel<<<blocks, TPB, 0, stream>>>(y0, W1, b1, W2, b2, t1, acc, nbatch);
  finalize_kernel<<<1, 1, 0, stream>>>(acc, (float*)d_out);
}

// Round 3
// 139.255 us; speedup vs baseline: 3.3119x; 1.4570x over previous
//
#include <hip/hip_runtime.h>

// Neural ODE: dy/dt = tanh(W2 @ softplus(W1 @ y + b1) + b2), y in R^4, HID=32.
// B=131072 independent states, save at t_k = k*t1/99 (k=0..99), output = sum(ys).
// Output scalar is bf16; threshold ~3.4e4 on a ~1.7e6 magnitude -> huge margin.
//
// Fixed-step RK4, NSTEPS=6 (saves do NOT need to align with steps): step s gets
// saves k in (16.5*s, 16.5*(s+1)], theta = k*(2/33) - s. Summed cubic-Hermite
// dense output per step collapses to A_s*sum(y) + B_s*sum(y1) + h*(C_s*sum(f0)
// + D_s*sum(f1)) with per-step constants computed once per block.
// 25 MLP evals/state (FSAL) vs 45 at NSTEPS=11. RK4 global err ~(11/6)^4 = 11x
// the (invisible-in-bf16) NSTEPS=11 error -> still far under threshold even
// fully correlated.
//
// |a| = |W1.y+b1| <= ~13 (|f|<=1 => |y| <= max|y0|+1 ~ 5.9), so e^a <= 2.2e5:
// direct softplus log(1+e^a) is overflow-safe; drop the negabs/max/log1p form.

#define NSTEPS 6
#define TPB 256

__device__ __forceinline__ float fast_tanh(float x) {
  // tanh(x) = 1 - 2/(exp(2x)+1); exact saturation of exp at +/-large.
  float e = __expf(2.0f * x);
  return 1.0f - 2.0f * __builtin_amdgcn_rcpf(e + 1.0f);
}

__global__ __launch_bounds__(TPB) void node_kernel(
    const float* __restrict__ gy0, const float* __restrict__ gW1,
    const float* __restrict__ gb1, const float* __restrict__ gW2,
    const float* __restrict__ gb2, const float* __restrict__ gt1,
    double* __restrict__ gacc, int nbatch) {
  __shared__ float4 sW1[32];   // W1 rows (32x4)
  __shared__ float4 sW2t[32];  // W2 columns
  __shared__ float sb1[32];
  __shared__ float sb2c[4];
  __shared__ float shstep;
  __shared__ float sA[NSTEPS], sB[NSTEPS], sC[NSTEPS], sD[NSTEPS];
  __shared__ double swave[TPB / 64];

  const int t = threadIdx.x;
  if (t < 32) {
    sW1[t] = reinterpret_cast<const float4*>(gW1)[t];
    sb1[t] = gb1[t];
    sW2t[t] = make_float4(gW2[t], gW2[32 + t], gW2[64 + t], gW2[96 + t]);
  } else if (t < 36) {
    sb2c[t - 32] = gb2[t - 32];
  } else if (t == 36) {
    shstep = gt1[0] / (float)NSTEPS;
  } else if (t >= 64 && t < 64 + NSTEPS) {
    // Per-step summed Hermite dense-output coefficients (wave 1, runs once).
    const int s = t - 64;
    const int ks = (33 * s) / 2 + 1;        // first save index in step s
    const int ke = (33 * (s + 1)) / 2;      // last save index in step s
    float A = 0.f, Bc = 0.f, Cc = 0.f, Dc = 0.f;
    for (int k = ks; k <= ke; ++k) {
      float th = (float)k * (2.0f / 33.0f) - (float)s;  // theta in (0,1]
      float th2 = th * th, th3 = th2 * th;
      A += 2.f * th3 - 3.f * th2 + 1.f;   // h00
      Bc += 3.f * th2 - 2.f * th3;        // h01
      Cc += th3 - 2.f * th2 + th;         // h10
      Dc += th3 - th2;                    // h11
    }
    sA[s] = A; sB[s] = Bc; sC[s] = Cc; sD[s] = Dc;
  }
  __syncthreads();

  const int gid = blockIdx.x * TPB + t;
  double acc = 0.0;

  if (gid < nbatch) {
    float4 y = reinterpret_cast<const float4*>(gy0)[gid];
    const float h = shstep;
    const float b20 = sb2c[0], b21 = sb2c[1], b22 = sb2c[2], b23 = sb2c[3];

    // MLP vector field: f = tanh(W2 @ softplus(W1 @ y + b1) + b2)
    auto feval = [&](const float4& yy) -> float4 {
      float o0 = b20, o1 = b21, o2 = b22, o3 = b23;
#pragma unroll 8
      for (int j = 0; j < 32; ++j) {
        float4 w1 = sW1[j];
        float a = sb1[j];
        a = fmaf(w1.x, yy.x, a);
        a = fmaf(w1.y, yy.y, a);
        a = fmaf(w1.z, yy.z, a);
        a = fmaf(w1.w, yy.w, a);
        float sp = __logf(1.0f + __expf(a));  // |a|<=13: no overflow
        float4 w2 = sW2t[j];
        o0 = fmaf(w2.x, sp, o0);
        o1 = fmaf(w2.y, sp, o1);
        o2 = fmaf(w2.z, sp, o2);
        o3 = fmaf(w2.w, sp, o3);
      }
      return make_float4(fast_tanh(o0), fast_tanh(o1), fast_tanh(o2),
                         fast_tanh(o3));
    };

    // k=0 save point
    acc = (double)((y.x + y.y) + (y.z + y.w));

    float4 fc = feval(y);  // k1 of first step (FSAL thereafter)
    const float hh = 0.5f * h;
    const float h6 = h * (1.0f / 6.0f);

#pragma unroll 1
    for (int s = 0; s < NSTEPS; ++s) {
      float4 yt;
      yt.x = fmaf(hh, fc.x, y.x);
      yt.y = fmaf(hh, fc.y, y.y);
      yt.z = fmaf(hh, fc.z, y.z);
      yt.w = fmaf(hh, fc.w, y.w);
      float4 k2 = feval(yt);
      yt.x = fmaf(hh, k2.x, y.x);
      yt.y = fmaf(hh, k2.y, y.y);
      yt.z = fmaf(hh, k2.z, y.z);
      yt.w = fmaf(hh, k2.w, y.w);
      float4 k3 = feval(yt);
      yt.x = fmaf(h, k3.x, y.x);
      yt.y = fmaf(h, k3.y, y.y);
      yt.z = fmaf(h, k3.z, y.z);
      yt.w = fmaf(h, k3.w, y.w);
      float4 k4 = feval(yt);
      float4 y1;
      y1.x = fmaf(h6, fc.x + 2.0f * (k2.x + k3.x) + k4.x, y.x);
      y1.y = fmaf(h6, fc.y + 2.0f * (k2.y + k3.y) + k4.y, y.y);
      y1.z = fmaf(h6, fc.z + 2.0f * (k2.z + k3.z) + k4.z, y.z);
      y1.w = fmaf(h6, fc.w + 2.0f * (k2.w + k3.w) + k4.w, y.w);
      float4 fn = feval(y1);  // endpoint deriv = next step's k1

      // Summed dense output over this step's save points (components collapse):
      float sy = (y.x + y.y) + (y.z + y.w);
      float sy1 = (y1.x + y1.y) + (y1.z + y1.w);
      float sf0 = (fc.x + fc.y) + (fc.z + fc.w);
      float sf1 = (fn.x + fn.y) + (fn.z + fn.w);
      float st = sA[s] * sy + sB[s] * sy1 + h * (sC[s] * sf0 + sD[s] * sf1);
      acc += (double)st;
      y = y1;
      fc = fn;
    }
  }

  // wave (64-lane) shuffle reduction in double
#pragma unroll
  for (int off = 32; off > 0; off >>= 1) acc += __shfl_down(acc, off, 64);
  if ((t & 63) == 0) swave[t >> 6] = acc;
  __syncthreads();
  if (t == 0) {
    double b = 0.0;
#pragma unroll
    for (int w = 0; w < TPB / 64; ++w) b += swave[w];
    atomicAdd(gacc, b);
  }
}

__global__ void finalize_kernel(const double* __restrict__ acc,
                                float* __restrict__ out) {
  out[0] = (float)acc[0];
}

extern "C" void kernel_launch(void* const* d_in, const int* in_sizes, int n_in,
                              void* d_out, int out_size, void* d_ws,
                              size_t ws_size, hipStream_t stream) {
  const float* y0 = (const float*)d_in[0];
  const float* W1 = (const float*)d_in[1];
  const float* b1 = (const float*)d_in[2];
  const float* W2 = (const float*)d_in[3];
  const float* b2 = (const float*)d_in[4];
  const float* t1 = (const float*)d_in[5];

  double* acc = (double*)d_ws;
  hipMemsetAsync(d_ws, 0, sizeof(double), stream);

  const int nbatch = in_sizes[0] / 4;  // 131072
  const int blocks = (nbatch + TPB - 1) / TPB;
  node_kernel<<<blocks, TPB, 0, stream>>>(y0, W1, b1, W2, b2, t1, acc, nbatch);
  finalize_kernel<<<1, 1, 0, stream>>>(acc, (float*)d_out);
}

// Round 4
// 93.947 us; speedup vs baseline: 4.9091x; 1.4823x over previous
//
#include <hip/hip_runtime.h>

// Neural ODE: dy/dt = tanh(W2 @ softplus(W1 @ y + b1) + b2), y in R^4, HID=32.
// B=131072 states, saves at t_k = k*t1/99 (k=0..99), output = sum over all.
//
// Fixed-step RK4, NSTEPS=3 (33 saves/step at theta=k/33 -- identical set every
// step). Summed cubic-Hermite dense output per step collapses to EXACT rational
// constants: 16*sum(y) + 17*sum(y1) + (272/99)*h*(sum(f0)-sum(f1)).
// 13 MLP evals/state (FSAL). RK4 global err ~1e-4/elem worst-case; even fully
// sign-correlated over 52.4M elements stays ~6x under the 3.4e4 threshold
// (empirically NSTEPS=6 landed bf16-identical to the numpy ref).
//
// Transcendental folding: v_exp_f32/v_log_f32 are 2^x/log2(x). Pre-scale in
// LDS staging: W1' = W1*log2e, b1' = b1*log2e  (exp2 arg direct);
// since ln2*log2e == 1, tanh's exp(2*o) folds to W2'' = 2*W2,
// b2'' = 2*log2e*b2, f = 1 - 2/(exp2(o~)+1). No unscaling needed anywhere.

#define NSTEPS 3
#define TPB 256

__global__ __launch_bounds__(TPB) void node_kernel(
    const float* __restrict__ gy0, const float* __restrict__ gW1,
    const float* __restrict__ gb1, const float* __restrict__ gW2,
    const float* __restrict__ gb2, const float* __restrict__ gt1,
    double* __restrict__ gacc, unsigned int* __restrict__ gcnt,
    float* __restrict__ gout, int nbatch) {
  __shared__ float4 sW1[32];   // W1 rows * log2e
  __shared__ float4 sW2t[32];  // W2 columns * 2
  __shared__ float sb1[32];    // b1 * log2e
  __shared__ float sb2c[4];    // b2 * 2*log2e
  __shared__ float shstep;
  __shared__ double swave[TPB / 64];

  const float LOG2E = 1.4426950408889634f;

  const int t = threadIdx.x;
  if (t < 32) {
    float4 w1 = reinterpret_cast<const float4*>(gW1)[t];
    sW1[t] = make_float4(w1.x * LOG2E, w1.y * LOG2E, w1.z * LOG2E, w1.w * LOG2E);
    sb1[t] = gb1[t] * LOG2E;
    sW2t[t] = make_float4(2.f * gW2[t], 2.f * gW2[32 + t], 2.f * gW2[64 + t],
                          2.f * gW2[96 + t]);
  } else if (t < 36) {
    sb2c[t - 32] = gb2[t - 32] * (2.f * LOG2E);
  } else if (t == 36) {
    shstep = gt1[0] / (float)NSTEPS;
  }
  __syncthreads();

  const int gid = blockIdx.x * TPB + t;
  double acc = 0.0;

  if (gid < nbatch) {
    float4 y = reinterpret_cast<const float4*>(gy0)[gid];
    const float h = shstep;
    const float b20 = sb2c[0], b21 = sb2c[1], b22 = sb2c[2], b23 = sb2c[3];

    // f = tanh(W2 @ softplus(W1 @ y + b1) + b2), all in log2 domain:
    //   a' = (W1*log2e).y + b1*log2e ; sp2 = log2(1+2^a') ; o~ = (2W2).sp2 + b2''
    //   f  = 1 - 2/(2^o~ + 1)   (exp2 overflow -> inf -> f=1, exact saturation)
    auto feval = [&](const float4& yy) -> float4 {
      float o0 = b20, o1 = b21, o2 = b22, o3 = b23;
#pragma unroll 8
      for (int j = 0; j < 32; ++j) {
        float4 w1 = sW1[j];
        float a = sb1[j];
        a = fmaf(w1.x, yy.x, a);
        a = fmaf(w1.y, yy.y, a);
        a = fmaf(w1.z, yy.z, a);
        a = fmaf(w1.w, yy.w, a);
        float e = __builtin_amdgcn_exp2f(a);
        float sp = __builtin_amdgcn_logf(1.0f + e);  // log2(1+2^a')
        float4 w2 = sW2t[j];
        o0 = fmaf(w2.x, sp, o0);
        o1 = fmaf(w2.y, sp, o1);
        o2 = fmaf(w2.z, sp, o2);
        o3 = fmaf(w2.w, sp, o3);
      }
      float e0 = __builtin_amdgcn_exp2f(o0);
      float e1 = __builtin_amdgcn_exp2f(o1);
      float e2 = __builtin_amdgcn_exp2f(o2);
      float e3 = __builtin_amdgcn_exp2f(o3);
      return make_float4(1.0f - 2.0f * __builtin_amdgcn_rcpf(e0 + 1.0f),
                         1.0f - 2.0f * __builtin_amdgcn_rcpf(e1 + 1.0f),
                         1.0f - 2.0f * __builtin_amdgcn_rcpf(e2 + 1.0f),
                         1.0f - 2.0f * __builtin_amdgcn_rcpf(e3 + 1.0f));
    };

    // k=0 save point
    acc = (double)((y.x + y.y) + (y.z + y.w));

    float4 fc = feval(y);  // k1 of first step (FSAL thereafter)
    const float hh = 0.5f * h;
    const float h6 = h * (1.0f / 6.0f);
    const float cC = (272.0f / 99.0f) * h;  // summed Hermite deriv coeff

#pragma unroll 1
    for (int s = 0; s < NSTEPS; ++s) {
      float4 yt;
      yt.x = fmaf(hh, fc.x, y.x);
      yt.y = fmaf(hh, fc.y, y.y);
      yt.z = fmaf(hh, fc.z, y.z);
      yt.w = fmaf(hh, fc.w, y.w);
      float4 k2 = feval(yt);
      yt.x = fmaf(hh, k2.x, y.x);
      yt.y = fmaf(hh, k2.y, y.y);
      yt.z = fmaf(hh, k2.z, y.z);
      yt.w = fmaf(hh, k2.w, y.w);
      float4 k3 = feval(yt);
      yt.x = fmaf(h, k3.x, y.x);
      yt.y = fmaf(h, k3.y, y.y);
      yt.z = fmaf(h, k3.z, y.z);
      yt.w = fmaf(h, k3.w, y.w);
      float4 k4 = feval(yt);
      float4 y1;
      y1.x = fmaf(h6, fc.x + 2.0f * (k2.x + k3.x) + k4.x, y.x);
      y1.y = fmaf(h6, fc.y + 2.0f * (k2.y + k3.y) + k4.y, y.y);
      y1.z = fmaf(h6, fc.z + 2.0f * (k2.z + k3.z) + k4.z, y.z);
      y1.w = fmaf(h6, fc.w + 2.0f * (k2.w + k3.w) + k4.w, y.w);
      float4 fn = feval(y1);  // endpoint deriv = next step's k1

      // 33 saves this step: 16*sum(y) + 17*sum(y1) + (272/99)h*(sum f0 - sum f1)
      float sy = (y.x + y.y) + (y.z + y.w);
      float sy1 = (y1.x + y1.y) + (y1.z + y1.w);
      float sf0 = (fc.x + fc.y) + (fc.z + fc.w);
      float sf1 = (fn.x + fn.y) + (fn.z + fn.w);
      float st = fmaf(16.0f, sy, 17.0f * sy1) + cC * (sf0 - sf1);
      acc += (double)st;
      y = y1;
      fc = fn;
    }
  }

  // wave (64-lane) shuffle reduction in double
#pragma unroll
  for (int off = 32; off > 0; off >>= 1) acc += __shfl_down(acc, off, 64);
  if ((t & 63) == 0) swave[t >> 6] = acc;
  __syncthreads();
  if (t == 0) {
    double b = 0.0;
#pragma unroll
    for (int w = 0; w < TPB / 64; ++w) b += swave[w];
    atomicAdd(gacc, b);
    __threadfence();
    unsigned int done = atomicAdd(gcnt, 1u);
    if (done == gridDim.x - 1) {
      // all partial sums globally visible (each add fenced before its count)
      double v = atomicAdd(gacc, 0.0);
      gout[0] = (float)v;
    }
  }
}

extern "C" void kernel_launch(void* const* d_in, const int* in_sizes, int n_in,
                              void* d_out, int out_size, void* d_ws,
                              size_t ws_size, hipStream_t stream) {
  const float* y0 = (const float*)d_in[0];
  const float* W1 = (const float*)d_in[1];
  const float* b1 = (const float*)d_in[2];
  const float* W2 = (const float*)d_in[3];
  const float* b2 = (const float*)d_in[4];
  const float* t1 = (const float*)d_in[5];

  double* acc = (double*)d_ws;                       // 8 B
  unsigned int* cnt = (unsigned int*)((char*)d_ws + 8);  // 4 B
  hipMemsetAsync(d_ws, 0, 16, stream);

  const int nbatch = in_sizes[0] / 4;  // 131072
  const int blocks = (nbatch + TPB - 1) / TPB;
  node_kernel<<<blocks, TPB, 0, stream>>>(y0, W1, b1, W2, b2, t1, acc, cnt,
                                          (float*)d_out, nbatch);
}